// Round 8
// baseline (2473.188 us; speedup 1.0000x reference)
//
#include <hip/hip_runtime.h>
#include <cstdint>
#include <cstddef>

// Problem constants (B, C, N, K from the reference)
#define BB_ 8
#define CC_ 128
#define NN_ 4096
#define KK_ 8

// ---- Scratch lives inside the out1 region (B*C*N*K = 33,554,432 floats). ----
// Viewed as 1024 slices ("bc" = b*128+c) of 32768 floats each:
//   bc 0        : xx   (dead after k_knn)
//   bc 1..8     : idx[b] bit-cast ints, idx[b][n][k] at IDX_OFF + b*32768 + n*8 + k
//   bc 9..136   : g[b][c][m] at G_OFF + (b*128+c)*4096 + m
//   bc 208..223 : pv  partial top-8 values  (dead after k_merge)
//   bc 224..239 : pi  partial top-8 indices (dead after k_merge)
// Write-once schedule: k_xx, k_knn, k_merge, k_gemm write scratch zones;
// k_out0 reads idx (writes out0 -> different buffer); k_gatherA writes bc
// 137..1023 (overwrites pv/pi only AFTER k_merge consumed them); k_gatherB
// writes bc 0..136 recomputing g on the fly, pre-loading its own idx rows.
#define XX_OFF  0
#define IDX_OFF 32768
#define G_OFF   294912
#define PV_OFF  6815744            // 208*32768
#define PI_OFF  7340032            // 224*32768

__device__ __forceinline__ float lrelu(float v) { return v >= 0.f ? v : 0.01f * v; }

// Phase-A streaming insert, DESC-tie rule: on equal value the NEW element
// (larger m, since each thread's stream is ascending in m) ranks ABOVE equals.
template <int S>
__device__ __forceinline__ void insert_tieup(float (&v)[S], int (&ix)[S], float d, int m) {
  if (d < v[S - 1]) return;              // d == v[S-1] must insert (new above)
  bool bs[S];
#pragma unroll
  for (int s = 0; s < S; ++s) bs[s] = (v[s] > d);   // strict: equal -> new above
#pragma unroll
  for (int s = S - 1; s >= 1; --s) {
    v[s]  = bs[s] ? v[s]  : (bs[s - 1] ? d : v[s - 1]);
    ix[s] = bs[s] ? ix[s] : (bs[s - 1] ? m : ix[s - 1]);
  }
  if (!bs[0]) { v[0] = d; ix[0] = m; }
}

// Merge comparator emulating np.argsort(d)[..., ::-1][..., :k]:
// value DESC, on bitwise-equal values index DESC (reversed stable ascending).
// This is a STRICT TOTAL ORDER over (v, m) pairs with distinct m, so the top-8
// of a candidate multiset is unique regardless of merge tree shape.
template <int S>
__device__ __forceinline__ void insert_ti_desc(float (&v)[S], int (&ix)[S], float d, int m) {
  bool stay = (v[S - 1] > d) || (v[S - 1] == d && ix[S - 1] > m);
  if (stay) return;
  bool bs[S];
#pragma unroll
  for (int s = 0; s < S; ++s) bs[s] = (v[s] > d) || (v[s] == d && ix[s] > m);
#pragma unroll
  for (int s = S - 1; s >= 1; --s) {
    v[s]  = bs[s] ? v[s]  : (bs[s - 1] ? d : v[s - 1]);
    ix[s] = bs[s] ? ix[s] : (bs[s - 1] ? m : ix[s - 1]);
  }
  if (!bs[0]) { v[0] = d; ix[0] = m; }
}

// ---------------- K1: xx[b,n] = sum_c x^2 (numpy: rounded products, sequential adds).
__global__ void k_xx(const float* __restrict__ x, float* __restrict__ out1f) {
  int t = blockIdx.x * 256 + threadIdx.x;
  int b = t >> 12, n = t & (NN_ - 1);
  const float* p = x + ((size_t)b * CC_) * NN_ + n;
  float acc = 0.f;
  {
#pragma clang fp contract(off)
#pragma unroll
    for (int c = 0; c < CC_; ++c) {
      float v = p[(size_t)c * NN_];
      float v2 = v * v;
      acc = acc + v2;
    }
  }
  out1f[XX_OFF + t] = acc;
}

// 16 FMAs x 4 c-lanes; accumulation order per (i,j) identical to previous
// passing kernel (x,y,z,w ascending c within granule, granules ascending).
__device__ __forceinline__ void fma16(float (&acc)[4][4], const float4 (&a)[4],
                                      const float4 (&b)[4]) {
#pragma unroll
  for (int i = 0; i < 4; ++i)
#pragma unroll
    for (int j = 0; j < 4; ++j) {
      acc[i][j] = fmaf(a[i].x, b[j].x, acc[i][j]);
      acc[i][j] = fmaf(a[i].y, b[j].y, acc[i][j]);
      acc[i][j] = fmaf(a[i].z, b[j].z, acc[i][j]);
      acc[i][j] = fmaf(a[i].w, b[j].w, acc[i][j]);
    }
}

// ---------------- K2: fused pairwise-distance + top-8 per row (np-fp32 emulation).
// v8 (this round): the r3 kernel (verified correct; lean 8-b128-per-granule LDS
// diet; 51.5 KB LDS) with ONE change: each block handles an m-HALF (h in
// {0,1}), doubling the grid to 1024 so 3 blocks/CU are actually RESIDENT
// (r3's 512-block grid physically capped residency at 2/CU -- the round-3
// blunder). 3 blocks/CU = 12 waves/CU = 3 waves/SIMD overlaps the ~656us LDS
// phase with the ~750us VALU phase instead of serializing them (the r1 sum).
// Each half emits an exact partial top-8 to pv/pi (r7-verified machinery);
// k_merge folds the two halves with the same total-order comparator =>
// final idx provably identical (merge-tree independence).
// Numerics: same fmaf chain c=0..127 ascending per (n,m) (split-B staging
// preserves c order), same ascending-m per-thread stream within each half,
// same exact comparator everywhere.
__global__ __launch_bounds__(256, 3) void k_knn(const float* __restrict__ x,
                                                float* __restrict__ out1f) {
  __shared__ __align__(16) union S {
    struct {
      float As[64 * 132];  // 33792 B, full c, staged once
      float Bs[64 * 68];   // 17408 B, one 64-c half per phase
      float xxm[64];       //   256 B
    } a;
    struct { float v[4 * 64 * 9]; int i[4 * 64 * 9]; } mg;  // 18432 B (aliases As)
  } s;

  const float* xxz = out1f + XX_OFF;
  float* pvz = out1f + PV_OFF;
  int*   piz = (int*)(out1f + PI_OFF);

  const int blk = blockIdx.x;
  const int b  = blk >> 7;             // 8 batches
  const int nt = (blk >> 1) & 63;      // 64 row-tiles per batch
  const int h  = blk & 1;              // m-range half
  const int n0 = nt << 6;              // *64
  const int m_base = h << 11;          // 0 or 2048
  const float* xb = x + ((size_t)b * CC_) * NN_;
  const int t = threadIdx.x;
  const int tr = t & 15, tc = t >> 4;  // rows tr+16i, cols tc*4+j
  const int r64 = t & 63, wv = t >> 6; // staging: row (=lane), wave id

  // Stage the 64 A-rows (n0..n0+63, all 128 c) once, b128 writes.
  {
#pragma unroll
    for (int q = 0; q < 8; ++q) {
      int g = wv + 4 * q;              // granule 0..31
      float4 tmp;
      tmp.x = xb[(size_t)(4 * g + 0) * NN_ + n0 + r64];
      tmp.y = xb[(size_t)(4 * g + 1) * NN_ + n0 + r64];
      tmp.z = xb[(size_t)(4 * g + 2) * NN_ + n0 + r64];
      tmp.w = xb[(size_t)(4 * g + 3) * NN_ + n0 + r64];
      *reinterpret_cast<float4*>(&s.a.As[r64 * 132 + 4 * g]) = tmp;
    }
  }

  float xr[4];
#pragma unroll
  for (int i = 0; i < 4; ++i) xr[i] = xxz[(b << 12) + n0 + tr + 16 * i];

  float lv[4][8]; int li[4][8];
#pragma unroll
  for (int i = 0; i < 4; ++i)
#pragma unroll
    for (int q = 0; q < 8; ++q) { lv[i][q] = -INFINITY; li[i][q] = 0x7FFFFFFF; }

  const float4* As4 = reinterpret_cast<const float4*>(s.a.As);  // row = 33 granules
  const float4* Bs4 = reinterpret_cast<const float4*>(s.a.Bs);  // row = 17 granules
  int rowA[4], rowB[4];
#pragma unroll
  for (int i = 0; i < 4; ++i) rowA[i] = (tr + 16 * i) * 33;
#pragma unroll
  for (int j = 0; j < 4; ++j) rowB[j] = (tc * 4 + j) * 17;

  for (int m0c = 0; m0c < 2048; m0c += 64) {
    const int m0 = m_base + m0c;
    float acc[4][4] = {};
#pragma unroll
    for (int p = 0; p < 2; ++p) {
      __syncthreads();  // protect Bs (prev phase) and xxm (prev chunk's selection)
      {
        // Stage B c-half p: rows m0..m0+63, c in [64p, 64p+64), b128 writes.
#pragma unroll
        for (int q = 0; q < 4; ++q) {
          int gl = wv + 4 * q;         // local granule 0..15
          int c0 = 64 * p + 4 * gl;
          float4 tmp;
          tmp.x = xb[(size_t)(c0 + 0) * NN_ + m0 + r64];
          tmp.y = xb[(size_t)(c0 + 1) * NN_ + m0 + r64];
          tmp.z = xb[(size_t)(c0 + 2) * NN_ + m0 + r64];
          tmp.w = xb[(size_t)(c0 + 3) * NN_ + m0 + r64];
          *reinterpret_cast<float4*>(&s.a.Bs[r64 * 68 + 4 * gl]) = tmp;
        }
        if (p == 0 && t < 64) s.a.xxm[t] = xxz[(b << 12) + m0 + t];
      }
      __syncthreads();

      // 16 granules of this c-half, ascending c (global g = 16p + gl).
#pragma unroll 2
      for (int gl = 0; gl < 16; ++gl) {
        float4 av[4], bv[4];
#pragma unroll
        for (int i = 0; i < 4; ++i) av[i] = As4[rowA[i] + 16 * p + gl];
#pragma unroll
        for (int j = 0; j < 4; ++j) bv[j] = Bs4[rowB[j] + gl];
        fma16(acc, av, bv);
      }
    }

    // Streaming selection (per-thread m-subset ascending; DESC-tie insert).
#pragma unroll
    for (int j = 0; j < 4; ++j) {
      float xm = s.a.xxm[tc * 4 + j];
      int m = m0 + tc * 4 + j;
#pragma unroll
      for (int i = 0; i < 4; ++i) {
        float d = (2.0f * acc[i][j] - xr[i]) - xm;
        insert_tieup<8>(lv[i], li[i], d, m);
      }
    }
  }

  // ---- Merge. Within each wave, the 4 holders of row tr+16i sit at lanes
  // l, l^16, l^32, l^48: butterfly-merge their sorted lists with the exact
  // comparator (total order => unique top-8, merge-tree-independent).
  __syncthreads();  // all tile reads done; As region is dead, mg may alias it
#pragma unroll
  for (int mk = 16; mk <= 32; mk <<= 1) {
#pragma unroll
    for (int i = 0; i < 4; ++i) {
      float pv[8]; int pi[8];
#pragma unroll
      for (int q = 0; q < 8; ++q) {
        pv[q] = __shfl_xor(lv[i][q], mk, 64);
        pi[q] = __shfl_xor(li[i][q], mk, 64);
      }
#pragma unroll
      for (int q = 0; q < 8; ++q) insert_ti_desc<8>(lv[i], li[i], pv[q], pi[q]);
    }
  }
  // One lane per (wave, tr) writes the wave-level top-8 for its 4 rows.
  if ((t & 63) < 16) {
#pragma unroll
    for (int i = 0; i < 4; ++i) {
      int base = wv * 576 + (tr + 16 * i) * 9;   // [4][64][9] padded
#pragma unroll
      for (int q = 0; q < 8; ++q) {
        s.mg.v[base + q] = lv[i][q];
        s.mg.i[base + q] = li[i][q];
      }
    }
  }
  __syncthreads();
  // Final: 64 threads merge the 4 per-wave lists for their row -> partial list.
  if (t < 64) {
    float bvv[8]; int bii[8];
#pragma unroll
    for (int q = 0; q < 8; ++q) { bvv[q] = s.mg.v[t * 9 + q]; bii[q] = s.mg.i[t * 9 + q]; }
#pragma unroll
    for (int w = 1; w < 4; ++w) {
      int base = w * 576 + t * 9;
#pragma unroll
      for (int q = 0; q < 8; ++q) insert_ti_desc<8>(bvv, bii, s.mg.v[base + q], s.mg.i[base + q]);
    }
    size_t rowg = (size_t)(b << 12) + n0 + t;    // global row id 0..32767
    float* pvp = pvz + (rowg * 2 + h) * 8;
    int*   pip = piz + (rowg * 2 + h) * 8;
#pragma unroll
    for (int q = 0; q < KK_; ++q) { pvp[q] = bvv[q]; pip[q] = bii[q]; }
  }
}

// ---------------- K2b: fold the two half-range partial top-8 lists -> idx.
// Same strict-total-order comparator => exact top-8 of the union.
__global__ void k_merge(float* __restrict__ out1f) {
  int row = blockIdx.x * 256 + threadIdx.x;      // 0..32767
  const float* pvz = out1f + PV_OFF;
  const int*   piz = (const int*)(out1f + PI_OFF);
  int* idxz = (int*)(out1f + IDX_OFF);
  const float* p0 = pvz + (size_t)row * 16;
  const int*   i0 = piz + (size_t)row * 16;
  float v[8]; int ix[8];
#pragma unroll
  for (int q = 0; q < 8; ++q) { v[q] = p0[q]; ix[q] = i0[q]; }
#pragma unroll
  for (int q = 0; q < 8; ++q) insert_ti_desc<8>(v, ix, p0[8 + q], i0[8 + q]);
#pragma unroll
  for (int q = 0; q < KK_; ++q) idxz[(size_t)row * 8 + q] = ix[q];
}

// ---------------- K3: g[b,o,m] = sum_c W2[o,c]*lrelu(x[b,c,m]) -> out1 G zone.
__global__ __launch_bounds__(256) void k_gemm(const float* __restrict__ x,
                                              const float* __restrict__ w2,
                                              float* __restrict__ out1f) {
  __shared__ __align__(16) float Ws[64][68];
  __shared__ __align__(16) float Fs[64][68];
  int bb = blockIdx.x >> 7;
  int r = blockIdx.x & 127;
  int o0 = (r >> 6) << 6;   // 0 or 64
  int m0 = (r & 63) << 6;
  const float* xb = x + ((size_t)bb * CC_) * NN_;
  float* gb = out1f + G_OFF + ((size_t)bb * CC_) * NN_;
  int t = threadIdx.x;
  int tm = t & 15, to = t >> 4;

  float acc[4][4] = {};
  for (int cc = 0; cc < CC_; cc += 64) {
    __syncthreads();
    {
      int cl = t & 63, q0 = t >> 6;   // q0 in 0..3
      for (int oo = q0; oo < 64; oo += 4) Ws[oo][cl] = w2[(o0 + oo) * CC_ + cc + cl];
      for (int c2 = q0; c2 < 64; c2 += 4) Fs[cl][c2] = lrelu(xb[(size_t)(cc + c2) * NN_ + m0 + cl]);
    }
    __syncthreads();
#pragma unroll 8
    for (int cq = 0; cq < 64; cq += 4) {
      float4 aw[4], bf[4];
#pragma unroll
      for (int i = 0; i < 4; ++i) aw[i] = *reinterpret_cast<const float4*>(&Ws[to + 16 * i][cq]);
#pragma unroll
      for (int j = 0; j < 4; ++j) bf[j] = *reinterpret_cast<const float4*>(&Fs[tm + 16 * j][cq]);
#pragma unroll
      for (int i = 0; i < 4; ++i)
#pragma unroll
        for (int j = 0; j < 4; ++j) {
          acc[i][j] = fmaf(aw[i].x, bf[j].x, acc[i][j]);
          acc[i][j] = fmaf(aw[i].y, bf[j].y, acc[i][j]);
          acc[i][j] = fmaf(aw[i].z, bf[j].z, acc[i][j]);
          acc[i][j] = fmaf(aw[i].w, bf[j].w, acc[i][j]);
        }
    }
  }
#pragma unroll
  for (int i = 0; i < 4; ++i)
#pragma unroll
    for (int j = 0; j < 4; ++j)
      gb[((size_t)(o0 + to + 16 * i)) * NN_ + m0 + tm + 16 * j] = acc[i][j];
}

// ---------------- K4: out0[b,c,n] = x + (sum_k lrelu(x[.,idx_k]) + lrelu(self))/9.
// Reads idx from out1 scratch, writes out0 (different buffer -> no hazards).
__global__ void k_out0(const float* __restrict__ x, const float* __restrict__ out1f,
                       float* __restrict__ out) {
  __shared__ int idxL[512];   // 64 n * 8 k
  int b = blockIdx.x >> 6, nt = blockIdx.x & 63;
  int n0 = nt << 6;
  int t = threadIdx.x;
  const int* ib = (const int*)(out1f + IDX_OFF) + (b << 15) + (n0 << 3);
  idxL[t] = ib[t];
  idxL[t + 256] = ib[t + 256];
  __syncthreads();
  int nl = t & 63, c0 = t >> 6;
  for (int c = c0; c < CC_; c += 4) {
    const float* row = x + ((size_t)b * CC_ + c) * NN_;
    float self = row[n0 + nl];
    float s = 0.f;
#pragma unroll
    for (int k = 0; k < KK_; ++k) s += lrelu(row[idxL[(nl << 3) + k]]);
    s += lrelu(self);   // reference feats order: 8 grouped then center
    out[((size_t)b * CC_ + c) * NN_ + n0 + nl] = fmaf(s, 1.0f / 9.0f, self);
  }
}

// ---------------- K5: gather for bc = 137..1023 (b=1 c>=9 and b=2..7 all c).
// Reads only scratch slices bc 1..136; writes bc >= 137 -> disjoint, safe
// (pv/pi zones at bc 208..239 are dead by now: k_merge already ran).
__global__ void k_gatherA(float* __restrict__ out1f) {
  int bc = 137 + blockIdx.x;
  int b = bc >> 7;
  const int* idxz = (const int*)(out1f + IDX_OFF) + (b << 15);
  const float* gs = out1f + G_OFF + (size_t)bc * (size_t)NN_;
  float* op = out1f + (size_t)bc * 32768;
  for (int e = threadIdx.x; e < 32768; e += 256) {
    op[e] = gs[idxz[e]];
  }
}

// ---------------- K6: produce bc = 0..136 (b=0 all c; b=1 c<=8), overwriting the
// scratch zones. Recomputes g-columns on the fly (no g reads). Pre-loads its own
// 512 idx entries (rows 32T..32T+31 for b=0,1) into LDS before any global write;
// its writes alias only idx entries of its OWN rows, so no cross-block hazard.
__global__ __launch_bounds__(256) void k_gatherB(const float* __restrict__ x,
                                                 const float* __restrict__ w2,
                                                 float* __restrict__ out1f) {
  __shared__ int idxL[512];          // col = bsel*256 + r*8 + k
  __shared__ float xcols[8][128];
  int T = blockIdx.x;                // rows 32T .. 32T+31
  int t = threadIdx.x;
  const int* idxz = (const int*)(out1f + IDX_OFF);
  idxL[t]       = idxz[0 * 32768 + ((T * 32) << 3) + t];
  idxL[t + 256] = idxz[1 * 32768 + ((T * 32) << 3) + t];
  __syncthreads();                   // all idx preloaded before ANY write

  for (int it = 0; it < 64; ++it) {
    int colbase = it * 8;
    {  // load phase: 32 threads per column, 8 columns
      int cg = t >> 5, lane = t & 31;
      int col = colbase + cg;
      int bsel = col >> 8;
      int m = idxL[col];
      const float* xb = x + ((size_t)bsel * CC_) * NN_;
#pragma unroll
      for (int q = 0; q < 4; ++q) {
        int c = lane + 32 * q;
        xcols[cg][c] = lrelu(xb[(size_t)c * NN_ + m]);
      }
    }
    __syncthreads();
    {  // compute phase: thread (cg, c0) does channels c0+32h of column cg
      int cg = t >> 5, c0 = t & 31;
      int col = colbase + cg;
      int bsel = col >> 8;
      int rk = col & 255;
      int n = T * 32 + (rk >> 3);
      int k = rk & 7;
      int hmax = (bsel == 0) ? 4 : 1;
      for (int h = 0; h < hmax; ++h) {
        int c = c0 + 32 * h;
        const float* wr = w2 + c * CC_;
        float acc = 0.f;
#pragma unroll 8
        for (int cc = 0; cc < CC_; ++cc) acc = fmaf(wr[cc], xcols[cg][cc], acc);
        if (bsel == 0 || c <= 8) {
          out1f[(size_t)(bsel * CC_ + c) * 32768 + (n << 3) + k] = acc;
        }
      }
    }
    __syncthreads();
  }
}

extern "C" void kernel_launch(void* const* d_in, const int* in_sizes, int n_in,
                              void* d_out, int out_size, void* d_ws, size_t ws_size,
                              hipStream_t stream) {
  const float* x  = (const float*)d_in[0];
  // d_in[1] (W) is mathematically irrelevant: mean(softmax, axis=2) == 1/9 exactly.
  const float* w2 = (const float*)d_in[2];

  float* out0  = (float*)d_out;
  float* out1f = out0 + (size_t)BB_ * CC_ * NN_;
  (void)d_ws; (void)ws_size;   // zero-workspace design: ws_size may be anything

  k_xx     <<<(BB_ * NN_) / 256,  256, 0, stream>>>(x, out1f);
  k_knn    <<<BB_ * 128,          256, 0, stream>>>(x, out1f);
  k_merge  <<<128,                256, 0, stream>>>(out1f);
  k_gemm   <<<BB_ * 128,          256, 0, stream>>>(x, w2, out1f);
  k_out0   <<<BB_ * 64,           256, 0, stream>>>(x, out1f, out0);
  k_gatherA<<<1024 - 137,         256, 0, stream>>>(out1f);
  k_gatherB<<<128,                256, 0, stream>>>(x, w2, out1f);
}

// Round 9
// 2302.694 us; speedup vs baseline: 1.0740x; 1.0740x over previous
//
#include <hip/hip_runtime.h>
#include <cstdint>
#include <cstddef>

// Problem constants (B, C, N, K from the reference)
#define BB_ 8
#define CC_ 128
#define NN_ 4096
#define KK_ 8

// ---- Scratch lives inside the out1 region (B*C*N*K = 33,554,432 floats). ----
// Viewed as 1024 slices ("bc" = b*128+c) of 32768 floats each:
//   bc 0        : xx    (dead after k_exact)
//   bc 1..8     : idx[b] bit-cast ints, idx[b][n][k] at IDX_OFF + b*32768 + n*8 + k
//   bc 9..136   : g[b][c][m] at G_OFF + (b*128+c)*4096 + m
//   bc 512..639 : xT[b][n][c] fp32 transpose      (dead after k_exact)
//   bc 640..703 : xh[b][n][c] bf16 (2/float slot) (dead after k_filter)
//   bc 704..959 : cand[row][256] int candidate m  (dead after k_exact)
// Launch order: k_prep, k_xx, k_filter, k_exact, k_gemm, k_out0, k_gatherA,
// k_gatherB. k_gatherA writes bc 137..1023, overwriting xT/xh/cand only after
// their last readers (k_filter/k_exact) completed. k_gatherB writes bc 0..136
// recomputing g on the fly, pre-loading its own idx rows first.
#define XX_OFF   0
#define IDX_OFF  32768
#define G_OFF    294912
#define XT_OFF   16777216          // 512*32768
#define XH_OFF   20971520          // 640*32768
#define CAND_OFF 23068672          // 704*32768

typedef __attribute__((ext_vector_type(8))) short bf16x8;
typedef __attribute__((ext_vector_type(4))) float f32x4;

__device__ __forceinline__ float lrelu(float v) { return v >= 0.f ? v : 0.01f * v; }

// fp32 -> bf16 round-to-nearest-even (data is finite; no NaN/Inf handling).
__device__ __forceinline__ unsigned short f2bf(float f) {
  unsigned int u = __float_as_uint(f);
  unsigned int r = (u + 0x7FFFu + ((u >> 16) & 1u)) >> 16;
  return (unsigned short)r;
}

// Phase-A streaming insert (approx filter; tie rule irrelevant for a superset).
template <int S>
__device__ __forceinline__ void insert_tieup(float (&v)[S], int (&ix)[S], float d, int m) {
  if (d < v[S - 1]) return;
  bool bs[S];
#pragma unroll
  for (int s = 0; s < S; ++s) bs[s] = (v[s] > d);
#pragma unroll
  for (int s = S - 1; s >= 1; --s) {
    v[s]  = bs[s] ? v[s]  : (bs[s - 1] ? d : v[s - 1]);
    ix[s] = bs[s] ? ix[s] : (bs[s - 1] ? m : ix[s - 1]);
  }
  if (!bs[0]) { v[0] = d; ix[0] = m; }
}

// Exact comparator emulating np.argsort(d)[..., ::-1][..., :k]:
// value DESC, on bitwise-equal values index DESC. STRICT TOTAL ORDER over
// (v, m) with distinct m => top-8 unique regardless of insertion/merge order.
template <int S>
__device__ __forceinline__ void insert_ti_desc(float (&v)[S], int (&ix)[S], float d, int m) {
  bool stay = (v[S - 1] > d) || (v[S - 1] == d && ix[S - 1] > m);
  if (stay) return;
  bool bs[S];
#pragma unroll
  for (int s = 0; s < S; ++s) bs[s] = (v[s] > d) || (v[s] == d && ix[s] > m);
#pragma unroll
  for (int s = S - 1; s >= 1; --s) {
    v[s]  = bs[s] ? v[s]  : (bs[s - 1] ? d : v[s - 1]);
    ix[s] = bs[s] ? ix[s] : (bs[s - 1] ? m : ix[s - 1]);
  }
  if (!bs[0]) { v[0] = d; ix[0] = m; }
}

// ---------------- K0: xT (fp32 bit-copy) + xh (bf16 RNE), both [b][n][c].
__global__ __launch_bounds__(256) void k_prep(const float* __restrict__ x,
                                              float* __restrict__ out1f) {
  __shared__ float Ls[64][132];
  int b = blockIdx.x >> 6, mt = blockIdx.x & 63;
  int m0 = mt << 6;
  int t = threadIdx.x;
  const float* xb = x + ((size_t)b * CC_) * NN_;
  {
    int ml = t & 63, c0 = t >> 6;
    for (int c = c0; c < CC_; c += 4) Ls[ml][c] = xb[(size_t)c * NN_ + m0 + ml];
  }
  __syncthreads();
  float* xTb = out1f + XT_OFF + (size_t)(b << 12) * CC_;
  unsigned short* xhb = (unsigned short*)(out1f + XH_OFF) + (size_t)(b << 12) * CC_;
  {
    int cl = t & 127, r0 = t >> 7;
    for (int r = r0; r < 64; r += 2) {
      float v = Ls[r][cl];
      xTb[(size_t)(m0 + r) * CC_ + cl] = v;
      xhb[(size_t)(m0 + r) * CC_ + cl] = f2bf(v);
    }
  }
}

// ---------------- K1: xx[b,n] = sum_c x^2 (numpy: rounded products, sequential adds).
__global__ void k_xx(const float* __restrict__ x, float* __restrict__ out1f) {
  int t = blockIdx.x * 256 + threadIdx.x;
  int b = t >> 12, n = t & (NN_ - 1);
  const float* p = x + ((size_t)b * CC_) * NN_ + n;
  float acc = 0.f;
  {
#pragma clang fp contract(off)
#pragma unroll
    for (int c = 0; c < CC_; ++c) {
      float v = p[(size_t)c * NN_];
      float v2 = v * v;
      acc = acc + v2;
    }
  }
  out1f[XX_OFF + t] = acc;
}

// ---------------- K2a: MFMA bf16 candidate filter.
// Block = 4 waves; wave w owns 16 n-rows (n0w..+15); block streams one m-HALF
// (h = blk&1, 128 16-m tiles). Per tile: C(16x16) = sum_kk mfma_16x16x32_bf16.
// A and B fragments load with IDENTICAL addressing from row-major-by-point xh
// (8 contiguous bf16 at [row][32*kk + 8*(lane>>4)]): any shared within-k
// permutation error cancels in the dot product. C-layout (m89-verified):
// col = lane&15 (m), row = 4*(lane>>4)+reg (n). Each lane keeps per-n top-8
// approx candidates over its m-residue class (m === lane&15 mod 16); classes
// partition m => 256 distinct candidates/row across lanes+halves. bf16 score
// error ~0.3 vs typical top-8 boundary gap ~1.3 => superset of the exact
// top-8 with overwhelming margin (needs 8 same-class values within ~0.6 of
// the boundary to fail).
__global__ __launch_bounds__(256) void k_filter(float* __restrict__ out1f) {
  const float* xxz = out1f + XX_OFF;
  const unsigned short* xhz = (const unsigned short*)(out1f + XH_OFF);
  int* candz = (int*)(out1f + CAND_OFF);

  const int blk = blockIdx.x;
  const int b  = blk >> 7;             // 8 batches
  const int nt = (blk >> 1) & 63;      // 64-n block tiles
  const int h  = blk & 1;              // m half
  const int t = threadIdx.x;
  const int w = t >> 6, l = t & 63;
  const int lj = l & 15, lq = l >> 4;  // m-col residue, k-chunk / n-subrow group
  const int n0w = (nt << 6) + (w << 4);

  const unsigned short* xhb = xhz + (size_t)(b << 12) * CC_;
  const float* xxb = xxz + (b << 12);

  // A fragments for the wave's 16 n-rows: lane supplies row n0w+lj, k-chunk lq.
  bf16x8 afr[4];
#pragma unroll
  for (int kk = 0; kk < 4; ++kk)
    afr[kk] = *(const bf16x8*)(xhb + (size_t)(n0w + lj) * CC_ + 32 * kk + 8 * lq);

  float lv[4][8]; int li[4][8];
#pragma unroll
  for (int r = 0; r < 4; ++r)
#pragma unroll
    for (int s = 0; s < 8; ++s) { lv[r][s] = -INFINITY; li[r][s] = 0x7FFFFFFF; }

  for (int mt2 = 0; mt2 < 128; ++mt2) {
    const int m0 = (h << 11) + (mt2 << 4);
    const unsigned short* bp = xhb + (size_t)(m0 + lj) * CC_ + 8 * lq;
    bf16x8 bfr[4];
#pragma unroll
    for (int kk = 0; kk < 4; ++kk) bfr[kk] = *(const bf16x8*)(bp + 32 * kk);
    float xm = xxb[m0 + lj];

    f32x4 c = {0.f, 0.f, 0.f, 0.f};
#pragma unroll
    for (int kk = 0; kk < 4; ++kk)
      c = __builtin_amdgcn_mfma_f32_16x16x32_bf16(afr[kk], bfr[kk], c, 0, 0, 0);

    const int m = m0 + lj;
#pragma unroll
    for (int r = 0; r < 4; ++r) {
      float s = fmaf(2.0f, c[r], -xm);   // per-row monotone approx score
      insert_tieup<8>(lv[r], li[r], s, m);
    }
  }

  // Write candidate indices: lane's rows are n0w + 4*lq + r; class lj; half h.
#pragma unroll
  for (int r = 0; r < 4; ++r) {
    size_t rowg = (size_t)(b << 12) + n0w + 4 * lq + r;
    int* cp = candz + rowg * 256 + h * 128 + lj * 8;
#pragma unroll
    for (int s = 0; s < 8; ++s) cp[s] = li[r][s];
  }
}

// ---------------- K2b: exact recheck. For each row, recompute the 256
// candidates' distances with the BIT-EXACT r1 chain (sequential fmaf over
// c = 0..127 ascending on fp32 xT; d = (2*acc - xr) - xm), then take top-8
// under the exact (v desc, m desc) total order. Result identical to the
// previously-passing full-scan kernel whenever the candidate set contains the
// true top-8 (see k_filter margin analysis).
__global__ __launch_bounds__(256) void k_exact(float* __restrict__ out1f) {
  const float* xxz = out1f + XX_OFF;
  const float* xTz = out1f + XT_OFF;
  const int* candz = (const int*)(out1f + CAND_OFF);
  int* idxz = (int*)(out1f + IDX_OFF);

  const int t = threadIdx.x;
  const int w = t >> 6, l = t & 63;
  const int lr = l >> 4, lj = l & 15;          // row-in-wave, candidate group
  const size_t rowg = (size_t)blockIdx.x * 16 + w * 4 + lr;   // 0..32767
  const int b = (int)(rowg >> 12);
  const int nloc = (int)(rowg & (NN_ - 1));
  const float* xTb = xTz + (size_t)(b << 12) * CC_;
  const float xr = xxz[rowg];

  const float4* ap = (const float4*)(xTb + (size_t)nloc * CC_);
  const int* cp = candz + rowg * 256 + lj * 16;

  float ev[8]; int ei[8];
#pragma unroll
  for (int s = 0; s < 8; ++s) { ev[s] = -INFINITY; ei[s] = 0x7FFFFFFF; }

  for (int j = 0; j < 16; ++j) {
    const int m = cp[j];
    const float4* bp4 = (const float4*)(xTb + (size_t)m * CC_);
    float acc = 0.f;
#pragma unroll 8
    for (int g = 0; g < 32; ++g) {
      float4 a4 = ap[g], b4 = bp4[g];
      acc = fmaf(a4.x, b4.x, acc);
      acc = fmaf(a4.y, b4.y, acc);
      acc = fmaf(a4.z, b4.z, acc);
      acc = fmaf(a4.w, b4.w, acc);
    }
    float d = (2.0f * acc - xr) - xxz[(size_t)(b << 12) + m];
    insert_ti_desc<8>(ev, ei, d, m);
  }

  // Butterfly-merge the 16 lanes of this row (masks 1,2,4,8 stay in-group).
#pragma unroll
  for (int mk = 1; mk <= 8; mk <<= 1) {
    float pv[8]; int pi[8];
#pragma unroll
    for (int s = 0; s < 8; ++s) {
      pv[s] = __shfl_xor(ev[s], mk, 64);
      pi[s] = __shfl_xor(ei[s], mk, 64);
    }
#pragma unroll
    for (int s = 0; s < 8; ++s) insert_ti_desc<8>(ev, ei, pv[s], pi[s]);
  }

  if (lj == 0) {
    int* op = idxz + rowg * 8;
#pragma unroll
    for (int q = 0; q < KK_; ++q) op[q] = ei[q];
  }
}

// ---------------- K3: g[b,o,m] = sum_c W2[o,c]*lrelu(x[b,c,m]) -> out1 G zone.
__global__ __launch_bounds__(256) void k_gemm(const float* __restrict__ x,
                                              const float* __restrict__ w2,
                                              float* __restrict__ out1f) {
  __shared__ __align__(16) float Ws[64][68];
  __shared__ __align__(16) float Fs[64][68];
  int bb = blockIdx.x >> 7;
  int r = blockIdx.x & 127;
  int o0 = (r >> 6) << 6;   // 0 or 64
  int m0 = (r & 63) << 6;
  const float* xb = x + ((size_t)bb * CC_) * NN_;
  float* gb = out1f + G_OFF + ((size_t)bb * CC_) * NN_;
  int t = threadIdx.x;
  int tm = t & 15, to = t >> 4;

  float acc[4][4] = {};
  for (int cc = 0; cc < CC_; cc += 64) {
    __syncthreads();
    {
      int cl = t & 63, q0 = t >> 6;   // q0 in 0..3
      for (int oo = q0; oo < 64; oo += 4) Ws[oo][cl] = w2[(o0 + oo) * CC_ + cc + cl];
      for (int c2 = q0; c2 < 64; c2 += 4) Fs[cl][c2] = lrelu(xb[(size_t)(cc + c2) * NN_ + m0 + cl]);
    }
    __syncthreads();
#pragma unroll 8
    for (int cq = 0; cq < 64; cq += 4) {
      float4 aw[4], bf[4];
#pragma unroll
      for (int i = 0; i < 4; ++i) aw[i] = *reinterpret_cast<const float4*>(&Ws[to + 16 * i][cq]);
#pragma unroll
      for (int j = 0; j < 4; ++j) bf[j] = *reinterpret_cast<const float4*>(&Fs[tm + 16 * j][cq]);
#pragma unroll
      for (int i = 0; i < 4; ++i)
#pragma unroll
        for (int j = 0; j < 4; ++j) {
          acc[i][j] = fmaf(aw[i].x, bf[j].x, acc[i][j]);
          acc[i][j] = fmaf(aw[i].y, bf[j].y, acc[i][j]);
          acc[i][j] = fmaf(aw[i].z, bf[j].z, acc[i][j]);
          acc[i][j] = fmaf(aw[i].w, bf[j].w, acc[i][j]);
        }
    }
  }
#pragma unroll
  for (int i = 0; i < 4; ++i)
#pragma unroll
    for (int j = 0; j < 4; ++j)
      gb[((size_t)(o0 + to + 16 * i)) * NN_ + m0 + tm + 16 * j] = acc[i][j];
}

// ---------------- K4: out0[b,c,n] = x + (sum_k lrelu(x[.,idx_k]) + lrelu(self))/9.
__global__ void k_out0(const float* __restrict__ x, const float* __restrict__ out1f,
                       float* __restrict__ out) {
  __shared__ int idxL[512];   // 64 n * 8 k
  int b = blockIdx.x >> 6, nt = blockIdx.x & 63;
  int n0 = nt << 6;
  int t = threadIdx.x;
  const int* ib = (const int*)(out1f + IDX_OFF) + (b << 15) + (n0 << 3);
  idxL[t] = ib[t];
  idxL[t + 256] = ib[t + 256];
  __syncthreads();
  int nl = t & 63, c0 = t >> 6;
  for (int c = c0; c < CC_; c += 4) {
    const float* row = x + ((size_t)b * CC_ + c) * NN_;
    float self = row[n0 + nl];
    float s = 0.f;
#pragma unroll
    for (int k = 0; k < KK_; ++k) s += lrelu(row[idxL[(nl << 3) + k]]);
    s += lrelu(self);   // reference feats order: 8 grouped then center
    out[((size_t)b * CC_ + c) * NN_ + n0 + nl] = fmaf(s, 1.0f / 9.0f, self);
  }
}

// ---------------- K5: gather for bc = 137..1023 (b=1 c>=9 and b=2..7 all c).
// Reads only scratch slices bc 1..136; writes bc >= 137 -> disjoint, safe
// (xT/xh/cand zones are dead: k_filter/k_exact already ran).
__global__ void k_gatherA(float* __restrict__ out1f) {
  int bc = 137 + blockIdx.x;
  int b = bc >> 7;
  const int* idxz = (const int*)(out1f + IDX_OFF) + (b << 15);
  const float* gs = out1f + G_OFF + (size_t)bc * (size_t)NN_;
  float* op = out1f + (size_t)bc * 32768;
  for (int e = threadIdx.x; e < 32768; e += 256) {
    op[e] = gs[idxz[e]];
  }
}

// ---------------- K6: produce bc = 0..136 (b=0 all c; b=1 c<=8), overwriting the
// scratch zones. Recomputes g-columns on the fly (no g reads). Pre-loads its own
// 512 idx entries into LDS before any global write.
__global__ __launch_bounds__(256) void k_gatherB(const float* __restrict__ x,
                                                 const float* __restrict__ w2,
                                                 float* __restrict__ out1f) {
  __shared__ int idxL[512];          // col = bsel*256 + r*8 + k
  __shared__ float xcols[8][128];
  int T = blockIdx.x;                // rows 32T .. 32T+31
  int t = threadIdx.x;
  const int* idxz = (const int*)(out1f + IDX_OFF);
  idxL[t]       = idxz[0 * 32768 + ((T * 32) << 3) + t];
  idxL[t + 256] = idxz[1 * 32768 + ((T * 32) << 3) + t];
  __syncthreads();                   // all idx preloaded before ANY write

  for (int it = 0; it < 64; ++it) {
    int colbase = it * 8;
    {  // load phase: 32 threads per column, 8 columns
      int cg = t >> 5, lane = t & 31;
      int col = colbase + cg;
      int bsel = col >> 8;
      int m = idxL[col];
      const float* xb = x + ((size_t)bsel * CC_) * NN_;
#pragma unroll
      for (int q = 0; q < 4; ++q) {
        int c = lane + 32 * q;
        xcols[cg][c] = lrelu(xb[(size_t)c * NN_ + m]);
      }
    }
    __syncthreads();
    {  // compute phase: thread (cg, c0) does channels c0+32h of column cg
      int cg = t >> 5, c0 = t & 31;
      int col = colbase + cg;
      int bsel = col >> 8;
      int rk = col & 255;
      int n = T * 32 + (rk >> 3);
      int k = rk & 7;
      int hmax = (bsel == 0) ? 4 : 1;
      for (int hh = 0; hh < hmax; ++hh) {
        int c = c0 + 32 * hh;
        const float* wr = w2 + c * CC_;
        float acc = 0.f;
#pragma unroll 8
        for (int cc = 0; cc < CC_; ++cc) acc = fmaf(wr[cc], xcols[cg][cc], acc);
        if (bsel == 0 || c <= 8) {
          out1f[(size_t)(bsel * CC_ + c) * 32768 + (n << 3) + k] = acc;
        }
      }
    }
    __syncthreads();
  }
}

extern "C" void kernel_launch(void* const* d_in, const int* in_sizes, int n_in,
                              void* d_out, int out_size, void* d_ws, size_t ws_size,
                              hipStream_t stream) {
  const float* x  = (const float*)d_in[0];
  // d_in[1] (W) is mathematically irrelevant: mean(softmax, axis=2) == 1/9 exactly.
  const float* w2 = (const float*)d_in[2];

  float* out0  = (float*)d_out;
  float* out1f = out0 + (size_t)BB_ * CC_ * NN_;
  (void)d_ws; (void)ws_size;   // zero-workspace design: ws_size may be anything

  k_prep   <<<BB_ * 64,           256, 0, stream>>>(x, out1f);
  k_xx     <<<(BB_ * NN_) / 256,  256, 0, stream>>>(x, out1f);
  k_filter <<<BB_ * 128,          256, 0, stream>>>(out1f);
  k_exact  <<<2048,               256, 0, stream>>>(out1f);
  k_gemm   <<<BB_ * 128,          256, 0, stream>>>(x, w2, out1f);
  k_out0   <<<BB_ * 64,           256, 0, stream>>>(x, out1f, out0);
  k_gatherA<<<1024 - 137,         256, 0, stream>>>(out1f);
  k_gatherB<<<128,                256, 0, stream>>>(x, w2, out1f);
}